// Round 1
// 1050.743 us; speedup vs baseline: 1.0662x; 1.0662x over previous
//
#include <hip/hip_runtime.h>
#include <hip/hip_bf16.h>
#include <stdint.h>

// ExpHashEncoder v3.
// Pass A (blend): blend 8 basis tables -> per-frame bf16 table in d_ws.
//   v3: fully coalesced loads. Block owns a contiguous 1024-entry chunk;
//   thread t handles entries base + k*256 + t, so every float2 load is
//   64-lane x 8B contiguous (was stride-32B scatter -> ~4x line-touch
//   amplification with nt/L1-bypass loads). nt reads keep the 456 MB basis
//   stream from evicting the freshly written cur table out of L2/L3.
// Pass B (gather): unchanged level-phased gather. Grid phase p: phase 0 =
//   dense levels 0-2, phases 1..13 = hash level p+2 (8 MB working set per
//   phase across 4 frames -> high per-XCD L2 residency).

static constexpr int      NPOINTS = 524288;
static constexpr size_t   TOTAL_T = 7131219;     // sum of per-level param counts
static constexpr uint32_t NENT    = 7131219u;    // same, as u32
static constexpr uint32_t TPAD    = 7131264;     // TOTAL_T rounded up to 64
static constexpr uint32_t BLEND_BLOCKS = (NENT + 1023u) / 1024u;  // 6965

#define OFFS_INIT {0u,4913u,40850u,315475u,839763u,1364051u,1888339u,2412627u, \
                   2936915u,3461203u,3985491u,4509779u,5034067u,5558355u,6082643u,6606931u}

__device__ __forceinline__ uint32_t pack_bf16x2(float a, float b) {
    __hip_bfloat162 h;
    h.x = __float2bfloat16(a);
    h.y = __float2bfloat16(b);
    uint32_t u;
    __builtin_memcpy(&u, &h, 4);
    return u;
}

__device__ __forceinline__ float2 unpack_bf16x2(uint32_t u) {
    float2 r;
    uint32_t lx = u << 16;
    uint32_t ly = u & 0xFFFF0000u;
    __builtin_memcpy(&r.x, &lx, 4);
    __builtin_memcpy(&r.y, &ly, 4);
    return r;
}

__device__ __forceinline__ float2 nt_load_f2(const float2* p) {
    uint64_t raw = __builtin_nontemporal_load((const uint64_t*)p);
    float2 r;
    __builtin_memcpy(&r, &raw, 8);
    return r;
}

// ---------------------------------------------------------------- blend
__global__ __launch_bounds__(256) void blend_coal_kernel(
    const float2* __restrict__ mean2, const float2* __restrict__ emb2,
    const float* __restrict__ expw, uint32_t* __restrict__ cur)
{
    // 32 blend weights: uniform address -> scalar loads, lives in SGPRs.
    float w[4][8];
#pragma unroll
    for (int f = 0; f < 4; ++f)
#pragma unroll
        for (int b = 0; b < 8; ++b)
            w[f][b] = expw[8 * f + b];

    uint32_t base = blockIdx.x * 1024u + threadIdx.x;

    if (blockIdx.x != BLEND_BLOCKS - 1u) {
        // full block: all 4 sub-chunks in range, no bounds checks.
#pragma unroll
        for (int k = 0; k < 4; ++k) {
            uint32_t idx = base + 256u * k;
            float2 m = nt_load_f2(&mean2[idx]);
            float ax[4], ay[4];
#pragma unroll
            for (int f = 0; f < 4; ++f) { ax[f] = w[f][0] * m.x; ay[f] = w[f][0] * m.y; }
#pragma unroll
            for (int b = 0; b < 7; ++b) {
                float2 v = nt_load_f2(&emb2[(size_t)b * TOTAL_T + idx]);
#pragma unroll
                for (int f = 0; f < 4; ++f) {
                    ax[f] = fmaf(w[f][b + 1], v.x, ax[f]);
                    ay[f] = fmaf(w[f][b + 1], v.y, ay[f]);
                }
            }
#pragma unroll
            for (int f = 0; f < 4; ++f)
                cur[(size_t)f * TPAD + idx] = pack_bf16x2(ax[f], ay[f]);
        }
    } else {
        // tail block: per-entry bounds check.
#pragma unroll
        for (int k = 0; k < 4; ++k) {
            uint32_t idx = base + 256u * k;
            if (idx >= NENT) return;   // idx monotone in k per thread
            float2 m = nt_load_f2(&mean2[idx]);
            float ax[4], ay[4];
#pragma unroll
            for (int f = 0; f < 4; ++f) { ax[f] = w[f][0] * m.x; ay[f] = w[f][0] * m.y; }
#pragma unroll
            for (int b = 0; b < 7; ++b) {
                float2 v = nt_load_f2(&emb2[(size_t)b * TOTAL_T + idx]);
#pragma unroll
                for (int f = 0; f < 4; ++f) {
                    ax[f] = fmaf(w[f][b + 1], v.x, ax[f]);
                    ay[f] = fmaf(w[f][b + 1], v.y, ay[f]);
                }
            }
#pragma unroll
            for (int f = 0; f < 4; ++f)
                cur[(size_t)f * TPAD + idx] = pack_bf16x2(ax[f], ay[f]);
        }
    }
}

// ---------------------------------------------------------------- gather
// grid = 14 phases * 2048 point-blocks; phase = blockIdx.x>>11 (dispatch order
// sweeps phases sequentially so concurrent blocks share one level's table).
__global__ __launch_bounds__(256) void gather_lvl_kernel(
    const float* __restrict__ xyz, const int* __restrict__ rays,
    const uint32_t* __restrict__ cur, float* __restrict__ out)
{
    uint32_t phase = blockIdx.x >> 11;
    uint32_t pb    = blockIdx.x & 2047u;
    uint32_t p     = pb * 256u + threadIdx.x;   // 2048*256 == NPOINTS exactly

    float x = xyz[3 * p + 0], y = xyz[3 * p + 1], z = xyz[3 * p + 2];
    uint32_t frame = ((uint32_t)rays[p]) >> 10;
    const uint32_t* __restrict__ tab = cur + (size_t)frame * TPAD;

    if (phase == 0) {
        // dense levels 0..2
        float o[6];
        const uint32_t ST[3]  = {17u, 33u, 65u};
        const uint32_t OFF[3] = {0u, 4913u, 40850u};
#pragma unroll
        for (int l = 0; l < 3; ++l) {
            float scale = (float)((16 << l) - 1);
            float px = fmaf(x, scale, 0.5f);
            float py = fmaf(y, scale, 0.5f);
            float pz = fmaf(z, scale, 0.5f);
            float fx = floorf(px), fy = floorf(py), fz = floorf(pz);
            float wx = px - fx, wy = py - fy, wz = pz - fz;
            uint32_t ix = (uint32_t)(int)fx, iy = (uint32_t)(int)fy, iz = (uint32_t)(int)fz;
            uint32_t st = ST[l], st2 = st * st, base = OFF[l];
            float sx = 0.f, sy = 0.f;
#pragma unroll
            for (int c = 0; c < 8; ++c) {
                uint32_t bx = (c >> 2) & 1, by = (c >> 1) & 1, bz = c & 1;
                uint32_t idx = base + (ix + bx) + (iy + by) * st + (iz + bz) * st2;
                float w = (bx ? wx : 1.f - wx) * (by ? wy : 1.f - wy) * (bz ? wz : 1.f - wz);
                float2 v = unpack_bf16x2(tab[idx]);
                sx = fmaf(w, v.x, sx);
                sy = fmaf(w, v.y, sy);
            }
            o[2 * l] = sx; o[2 * l + 1] = sy;
        }
        float* ob = out + (size_t)p * 32;
        *(float4*)ob       = make_float4(o[0], o[1], o[2], o[3]);
        *(float2*)(ob + 4) = make_float2(o[4], o[5]);
    } else {
        // hash level l = phase + 2
        int l = (int)phase + 2;
        float scale = (float)((16 << l) - 1);
        uint32_t base = 315475u + ((phase - 1u) << 19);
        float px = fmaf(x, scale, 0.5f);
        float py = fmaf(y, scale, 0.5f);
        float pz = fmaf(z, scale, 0.5f);
        float fx = floorf(px), fy = floorf(py), fz = floorf(pz);
        float wx = px - fx, wy = py - fy, wz = pz - fz;
        uint32_t ix = (uint32_t)(int)fx, iy = (uint32_t)(int)fy, iz = (uint32_t)(int)fz;
        float sx = 0.f, sy = 0.f;
#pragma unroll
        for (int c = 0; c < 8; ++c) {
            uint32_t bx = (c >> 2) & 1, by = (c >> 1) & 1, bz = c & 1;
            uint32_t h = (ix + bx)
                       ^ ((iy + by) * 2654435761u)
                       ^ ((iz + bz) * 805459861u);
            uint32_t idx = base + (h & 0x7FFFFu);
            float w = (bx ? wx : 1.f - wx) * (by ? wy : 1.f - wy) * (bz ? wz : 1.f - wz);
            float2 v = unpack_bf16x2(tab[idx]);
            sx = fmaf(w, v.x, sx);
            sy = fmaf(w, v.y, sy);
        }
        *(float2*)(out + (size_t)p * 32 + 2 * l) = make_float2(sx, sy);
    }
}

// ------------------------------------------------- fused fallback (tiny ws)
__global__ __launch_bounds__(256) void fused_fallback_kernel(
    const float* __restrict__ xyz, const int* __restrict__ rays,
    const float* __restrict__ expw,
    const float2* __restrict__ mean, const float2* __restrict__ emb,
    float* __restrict__ out)
{
    int p = blockIdx.x * 256 + threadIdx.x;
    if (p >= NPOINTS) return;
    float x = xyz[3 * p], y = xyz[3 * p + 1], z = xyz[3 * p + 2];
    int frame = rays[p] >> 10;
    float e[8];
#pragma unroll
    for (int b = 0; b < 8; ++b) e[b] = expw[8 * frame + b];

    constexpr uint32_t OFFS[16] = OFFS_INIT;

    for (int l = 0; l < 16; ++l) {
        float scale = (float)((16 << l) - 1);
        float px = fmaf(x, scale, 0.5f);
        float py = fmaf(y, scale, 0.5f);
        float pz = fmaf(z, scale, 0.5f);
        float fx = floorf(px), fy = floorf(py), fz = floorf(pz);
        float wx = px - fx, wy = py - fy, wz = pz - fz;
        int ix = (int)fx, iy = (int)fy, iz = (int)fz;
        uint32_t base = OFFS[l];
        float sx = 0.f, sy = 0.f;
#pragma unroll
        for (int c = 0; c < 8; ++c) {
            int bx = (c >> 2) & 1, by = (c >> 1) & 1, bz = c & 1;
            uint32_t idx;
            if (l < 3) {
                uint32_t st = (l == 0) ? 17u : (l == 1) ? 33u : 65u;
                idx = (uint32_t)(ix + bx) + (uint32_t)(iy + by) * st
                    + (uint32_t)(iz + bz) * st * st;
            } else {
                idx = ((uint32_t)(ix + bx)
                     ^ ((uint32_t)(iy + by) * 2654435761u)
                     ^ ((uint32_t)(iz + bz) * 805459861u)) & 0x7FFFFu;
            }
            uint32_t g = base + idx;
            float2 m = mean[g];
            float vx = e[0] * m.x, vy = e[0] * m.y;
#pragma unroll
            for (int b = 0; b < 7; ++b) {
                float2 t = emb[(size_t)b * TOTAL_T + g];
                vx = fmaf(e[1 + b], t.x, vx);
                vy = fmaf(e[1 + b], t.y, vy);
            }
            float w = (bx ? wx : 1.f - wx) * (by ? wy : 1.f - wy) * (bz ? wz : 1.f - wz);
            sx = fmaf(w, vx, sx);
            sy = fmaf(w, vy, sy);
        }
        out[(size_t)p * 32 + 2 * l]     = sx;
        out[(size_t)p * 32 + 2 * l + 1] = sy;
    }
}

// ---------------------------------------------------------------- launch
extern "C" void kernel_launch(void* const* d_in, const int* in_sizes, int n_in,
                              void* d_out, int out_size, void* d_ws, size_t ws_size,
                              hipStream_t stream) {
    const float* inputs = (const float*)d_in[0];
    const float* expw   = (const float*)d_in[1];
    const float* mean   = (const float*)d_in[2];
    const float* emb    = (const float*)d_in[3];
    const int*   rays   = (const int*)d_in[4];
    float* out = (float*)d_out;

    const size_t need_bf16 = (size_t)4 * TPAD * 4;  // 114,100,224 B

    if (ws_size >= need_bf16) {
        uint32_t* cur = (uint32_t*)d_ws;
        blend_coal_kernel<<<BLEND_BLOCKS, 256, 0, stream>>>(
            (const float2*)mean, (const float2*)emb, expw, cur);
        gather_lvl_kernel<<<14 * 2048, 256, 0, stream>>>(
            inputs, rays, cur, out);
    } else {
        fused_fallback_kernel<<<NPOINTS / 256, 256, 0, stream>>>(
            inputs, rays, expw, (const float2*)mean, (const float2*)emb, out);
    }
}

// Round 4
// 940.054 us; speedup vs baseline: 1.1918x; 1.1177x over previous
//
#include <hip/hip_runtime.h>
#include <hip/hip_bf16.h>
#include <stdint.h>

// ExpHashEncoder v4c. Same algorithm as v4/v4b; sort_scatter's ballot/shfl
// leader election replaced with a per-block LDS-histogram ranking (boring,
// well-trodden) to remove the only exotic code path between the working v3
// and the two container failures.
//
// Pass A (blend): all 32 stream loads hoisted into regs before any FMA
//   (v3 serialized load->fma: ~1 outstanding load/wave -> 1.2 TB/s observed.
//   Hoisting gives 32 outstanding x 512B coalesced loads per wave).
// Sort: 4-bucket counting sort of points by frame. Output is order-invariant
//   (merge indexes through sperm), so atomic nondeterminism is benign.
// Pass B (gather): level-phased; blocks cover frame-sorted point ranges with
//   an XCD swizzle (dispatch%8 -> frame group) so each XCD L2 caches ONE
//   frame's 2 MB level table instead of all 4 frames' 8 MB (was ~1.3 GB of
//   duplicate per-XCD L2 fills). Results go to a compact per-level ws
//   (full-line coalesced writes in sorted order).
// Merge: per point, read 16 float2 from ws, write one full 128B out line.

static constexpr int      NPOINTS = 524288;
static constexpr size_t   TOTAL_T = 7131219;     // sum of per-level param counts
static constexpr uint32_t NENT    = 7131219u;
static constexpr uint32_t TPAD    = 7131264;     // TOTAL_T rounded up to 64
static constexpr uint32_t BLEND_BLOCKS = (NENT + 1023u) / 1024u;  // 6965

// d_ws layout (byte offsets, all 256-aligned)
static constexpr size_t OFF_CUR   = 0;                       // 114,100,224 B
static constexpr size_t OFF_SXYZF = 114100224;               // 8,388,608 B (float4/point)
static constexpr size_t OFF_SPERM = OFF_SXYZF + 8388608;     // 2,097,152 B
static constexpr size_t OFF_CTRS  = OFF_SPERM + 2097152;     // 256 B (counts[4], cursor[4])
static constexpr size_t OFF_WS    = OFF_CTRS + 256;          // 67,108,864 B (16 lvl x N float2)
static constexpr size_t NEED_V4   = OFF_WS + 67108864;       // 191,695,104 B
static constexpr size_t NEED_V3   = 114100224;

#define OFFS_INIT {0u,4913u,40850u,315475u,839763u,1364051u,1888339u,2412627u, \
                   2936915u,3461203u,3985491u,4509779u,5034067u,5558355u,6082643u,6606931u}

__device__ __forceinline__ uint32_t pack_bf16x2(float a, float b) {
    __hip_bfloat162 h;
    h.x = __float2bfloat16(a);
    h.y = __float2bfloat16(b);
    uint32_t u;
    __builtin_memcpy(&u, &h, 4);
    return u;
}

__device__ __forceinline__ float2 unpack_bf16x2(uint32_t u) {
    float2 r;
    uint32_t lx = u << 16;
    uint32_t ly = u & 0xFFFF0000u;
    __builtin_memcpy(&r.x, &lx, 4);
    __builtin_memcpy(&r.y, &ly, 4);
    return r;
}

__device__ __forceinline__ float2 nt_load_f2(const float2* p) {
    uint64_t raw = __builtin_nontemporal_load((const uint64_t*)p);
    float2 r;
    __builtin_memcpy(&r, &raw, 8);
    return r;
}

// ---------------------------------------------------------------- blend
__global__ __launch_bounds__(256) void blend_mlp_kernel(
    const float2* __restrict__ mean2, const float2* __restrict__ emb2,
    const float* __restrict__ expw, uint32_t* __restrict__ cur)
{
    float w[4][8];
#pragma unroll
    for (int f = 0; f < 4; ++f)
#pragma unroll
        for (int b = 0; b < 8; ++b)
            w[f][b] = expw[8 * f + b];

    uint32_t base = blockIdx.x * 1024u + threadIdx.x;

    if (blockIdx.x != BLEND_BLOCKS - 1u) {
        // ALL 32 loads issued before any FMA: 32 outstanding x 512B/wave.
        float2 v[4][8];
#pragma unroll
        for (int k = 0; k < 4; ++k) {
            uint32_t idx = base + 256u * k;
            v[k][0] = nt_load_f2(&mean2[idx]);
#pragma unroll
            for (int b = 0; b < 7; ++b)
                v[k][1 + b] = nt_load_f2(&emb2[(size_t)b * TOTAL_T + idx]);
        }
#pragma unroll
        for (int k = 0; k < 4; ++k) {
            uint32_t idx = base + 256u * k;
            float ax[4], ay[4];
#pragma unroll
            for (int f = 0; f < 4; ++f) { ax[f] = w[f][0] * v[k][0].x; ay[f] = w[f][0] * v[k][0].y; }
#pragma unroll
            for (int b = 0; b < 7; ++b)
#pragma unroll
                for (int f = 0; f < 4; ++f) {
                    ax[f] = fmaf(w[f][b + 1], v[k][1 + b].x, ax[f]);
                    ay[f] = fmaf(w[f][b + 1], v[k][1 + b].y, ay[f]);
                }
#pragma unroll
            for (int f = 0; f < 4; ++f)
                cur[(size_t)f * TPAD + idx] = pack_bf16x2(ax[f], ay[f]);
        }
    } else {
        // tail block (83 entries): simple serial path.
#pragma unroll
        for (int k = 0; k < 4; ++k) {
            uint32_t idx = base + 256u * k;
            if (idx >= NENT) continue;
            float2 m = mean2[idx];
            float ax[4], ay[4];
#pragma unroll
            for (int f = 0; f < 4; ++f) { ax[f] = w[f][0] * m.x; ay[f] = w[f][0] * m.y; }
#pragma unroll
            for (int b = 0; b < 7; ++b) {
                float2 e = emb2[(size_t)b * TOTAL_T + idx];
#pragma unroll
                for (int f = 0; f < 4; ++f) {
                    ax[f] = fmaf(w[f][b + 1], e.x, ax[f]);
                    ay[f] = fmaf(w[f][b + 1], e.y, ay[f]);
                }
            }
#pragma unroll
            for (int f = 0; f < 4; ++f)
                cur[(size_t)f * TPAD + idx] = pack_bf16x2(ax[f], ay[f]);
        }
    }
}

// ---------------------------------------------------------------- sort
__global__ void sort_init_kernel(uint32_t* ctrs) {
    if (threadIdx.x < 16) ctrs[threadIdx.x] = 0u;
}

__global__ __launch_bounds__(256) void sort_count_kernel(
    const int* __restrict__ rays, uint32_t* __restrict__ ctrs)
{
    __shared__ uint32_t h[4];
    if (threadIdx.x < 4) h[threadIdx.x] = 0u;
    __syncthreads();
    uint32_t p = blockIdx.x * 256u + threadIdx.x;
    uint32_t f = (((uint32_t)rays[p]) >> 10) & 3u;
    atomicAdd(&h[f], 1u);
    __syncthreads();
    if (threadIdx.x < 4) atomicAdd(&ctrs[threadIdx.x], h[threadIdx.x]);
}

// Per-block LDS-histogram ranking: each thread gets a unique within-block
// offset via LDS atomicAdd; one global atomicAdd per (block,bucket) claims
// the block's base. ~8192 global atomics total.
__global__ __launch_bounds__(256) void sort_scatter_kernel(
    const float* __restrict__ xyz, const int* __restrict__ rays,
    uint32_t* __restrict__ ctrs,
    uint32_t* __restrict__ sperm, float4* __restrict__ sxyzf)
{
    __shared__ uint32_t hcnt[4];
    __shared__ uint32_t hbase[4];
    if (threadIdx.x < 4) hcnt[threadIdx.x] = 0u;
    __syncthreads();

    uint32_t p = blockIdx.x * 256u + threadIdx.x;
    uint32_t f = (((uint32_t)rays[p]) >> 10) & 3u;
    uint32_t myofs = atomicAdd(&hcnt[f], 1u);
    __syncthreads();

    if (threadIdx.x < 4)
        hbase[threadIdx.x] = atomicAdd(&ctrs[4 + threadIdx.x], hcnt[threadIdx.x]);
    __syncthreads();

    uint32_t c0 = ctrs[0], c1 = ctrs[1], c2 = ctrs[2];
    uint32_t bucket_base = (f == 0) ? 0u : (f == 1) ? c0 : (f == 2) ? (c0 + c1) : (c0 + c1 + c2);
    uint32_t slot = bucket_base + hbase[f] + myofs;
    if (slot >= (uint32_t)NPOINTS) slot = NPOINTS - 1;  // defensive; unreachable

    uint32_t packed = p | (f << 20);
    sperm[slot] = packed;
    float x = xyz[3 * p], y = xyz[3 * p + 1], z = xyz[3 * p + 2];
    float4 q; q.x = x; q.y = y; q.z = z; q.w = __uint_as_float(packed);
    sxyzf[slot] = q;
}

// ---------------------------------------------------------------- gather
// grid = 14 phases * 2048 blocks. Within a phase, swizzle so that
// XCD (dispatch%8) -> frame group (dispatch%8)>>1: each XCD L2 caches ONE
// frame's 2 MB level table. Frame is still taken per-lane from sxyzf.w,
// so bucket-boundary-straddling blocks stay correct.
__global__ __launch_bounds__(256) void gather_lvl_kernel(
    const float4* __restrict__ sxyzf, const uint32_t* __restrict__ cur,
    float2* __restrict__ ws)
{
    uint32_t phase  = blockIdx.x >> 11;
    uint32_t gl     = blockIdx.x & 2047u;
    uint32_t fgrp   = (gl & 7u) >> 1;
    uint32_t within = (gl >> 3) * 2u + (gl & 1u);
    uint32_t b      = fgrp * 512u + within;
    uint32_t j      = b * 256u + threadIdx.x;

    float4 q = sxyzf[j];
    float x = q.x, y = q.y, z = q.z;
    uint32_t f = (__float_as_uint(q.w) >> 20) & 3u;
    const uint32_t* __restrict__ tab = cur + (size_t)f * TPAD;

    if (phase == 0) {
        const uint32_t ST[3]  = {17u, 33u, 65u};
        const uint32_t OFF[3] = {0u, 4913u, 40850u};
#pragma unroll
        for (int l = 0; l < 3; ++l) {
            float scale = (float)((16 << l) - 1);
            float px = fmaf(x, scale, 0.5f);
            float py = fmaf(y, scale, 0.5f);
            float pz = fmaf(z, scale, 0.5f);
            float fx = floorf(px), fy = floorf(py), fz = floorf(pz);
            float wx = px - fx, wy = py - fy, wz = pz - fz;
            uint32_t ix = (uint32_t)(int)fx, iy = (uint32_t)(int)fy, iz = (uint32_t)(int)fz;
            uint32_t st = ST[l], st2 = st * st, base = OFF[l];
            float sx = 0.f, sy = 0.f;
#pragma unroll
            for (int c = 0; c < 8; ++c) {
                uint32_t bx = (c >> 2) & 1, by = (c >> 1) & 1, bz = c & 1;
                uint32_t idx = base + (ix + bx) + (iy + by) * st + (iz + bz) * st2;
                float w = (bx ? wx : 1.f - wx) * (by ? wy : 1.f - wy) * (bz ? wz : 1.f - wz);
                float2 v = unpack_bf16x2(tab[idx]);
                sx = fmaf(w, v.x, sx);
                sy = fmaf(w, v.y, sy);
            }
            ws[(size_t)l * NPOINTS + j] = make_float2(sx, sy);
        }
    } else {
        int l = (int)phase + 2;
        float scale = (float)((16 << l) - 1);
        uint32_t base = 315475u + ((phase - 1u) << 19);
        float px = fmaf(x, scale, 0.5f);
        float py = fmaf(y, scale, 0.5f);
        float pz = fmaf(z, scale, 0.5f);
        float fx = floorf(px), fy = floorf(py), fz = floorf(pz);
        float wx = px - fx, wy = py - fy, wz = pz - fz;
        uint32_t ix = (uint32_t)(int)fx, iy = (uint32_t)(int)fy, iz = (uint32_t)(int)fz;
        float sx = 0.f, sy = 0.f;
#pragma unroll
        for (int c = 0; c < 8; ++c) {
            uint32_t bx = (c >> 2) & 1, by = (c >> 1) & 1, bz = c & 1;
            uint32_t h = (ix + bx)
                       ^ ((iy + by) * 2654435761u)
                       ^ ((iz + bz) * 805459861u);
            uint32_t idx = base + (h & 0x7FFFFu);
            float w = (bx ? wx : 1.f - wx) * (by ? wy : 1.f - wy) * (bz ? wz : 1.f - wz);
            float2 v = unpack_bf16x2(tab[idx]);
            sx = fmaf(w, v.x, sx);
            sy = fmaf(w, v.y, sy);
        }
        ws[(size_t)l * NPOINTS + j] = make_float2(sx, sy);
    }
}

// ---------------------------------------------------------------- merge
__global__ __launch_bounds__(256) void merge_out_kernel(
    const uint32_t* __restrict__ sperm, const float2* __restrict__ ws,
    float* __restrict__ out)
{
    uint32_t j = blockIdx.x * 256u + threadIdx.x;
    uint32_t p = sperm[j] & 0xFFFFFu;
    if (p >= (uint32_t)NPOINTS) p = NPOINTS - 1;  // defensive; unreachable
    float4 o[8];
#pragma unroll
    for (int l = 0; l < 16; l += 2) {
        float2 a = ws[(size_t)l * NPOINTS + j];
        float2 c = ws[(size_t)(l + 1) * NPOINTS + j];
        o[l >> 1] = make_float4(a.x, a.y, c.x, c.y);
    }
    float* ob = out + (size_t)p * 32;
#pragma unroll
    for (int k = 0; k < 8; ++k)
        *(float4*)(ob + 4 * k) = o[k];
}

// -------------------------------------------- legacy gather (v3 fallback)
__global__ __launch_bounds__(256) void gather_legacy_kernel(
    const float* __restrict__ xyz, const int* __restrict__ rays,
    const uint32_t* __restrict__ cur, float* __restrict__ out)
{
    uint32_t phase = blockIdx.x >> 11;
    uint32_t pb    = blockIdx.x & 2047u;
    uint32_t p     = pb * 256u + threadIdx.x;

    float x = xyz[3 * p + 0], y = xyz[3 * p + 1], z = xyz[3 * p + 2];
    uint32_t frame = (((uint32_t)rays[p]) >> 10) & 3u;
    const uint32_t* __restrict__ tab = cur + (size_t)frame * TPAD;

    if (phase == 0) {
        float o[6];
        const uint32_t ST[3]  = {17u, 33u, 65u};
        const uint32_t OFF[3] = {0u, 4913u, 40850u};
#pragma unroll
        for (int l = 0; l < 3; ++l) {
            float scale = (float)((16 << l) - 1);
            float px = fmaf(x, scale, 0.5f);
            float py = fmaf(y, scale, 0.5f);
            float pz = fmaf(z, scale, 0.5f);
            float fx = floorf(px), fy = floorf(py), fz = floorf(pz);
            float wx = px - fx, wy = py - fy, wz = pz - fz;
            uint32_t ix = (uint32_t)(int)fx, iy = (uint32_t)(int)fy, iz = (uint32_t)(int)fz;
            uint32_t st = ST[l], st2 = st * st, base = OFF[l];
            float sx = 0.f, sy = 0.f;
#pragma unroll
            for (int c = 0; c < 8; ++c) {
                uint32_t bx = (c >> 2) & 1, by = (c >> 1) & 1, bz = c & 1;
                uint32_t idx = base + (ix + bx) + (iy + by) * st + (iz + bz) * st2;
                float w = (bx ? wx : 1.f - wx) * (by ? wy : 1.f - wy) * (bz ? wz : 1.f - wz);
                float2 v = unpack_bf16x2(tab[idx]);
                sx = fmaf(w, v.x, sx);
                sy = fmaf(w, v.y, sy);
            }
            o[2 * l] = sx; o[2 * l + 1] = sy;
        }
        float* ob = out + (size_t)p * 32;
        *(float4*)ob       = make_float4(o[0], o[1], o[2], o[3]);
        *(float2*)(ob + 4) = make_float2(o[4], o[5]);
    } else {
        int l = (int)phase + 2;
        float scale = (float)((16 << l) - 1);
        uint32_t base = 315475u + ((phase - 1u) << 19);
        float px = fmaf(x, scale, 0.5f);
        float py = fmaf(y, scale, 0.5f);
        float pz = fmaf(z, scale, 0.5f);
        float fx = floorf(px), fy = floorf(py), fz = floorf(pz);
        float wx = px - fx, wy = py - fy, wz = pz - fz;
        uint32_t ix = (uint32_t)(int)fx, iy = (uint32_t)(int)fy, iz = (uint32_t)(int)fz;
        float sx = 0.f, sy = 0.f;
#pragma unroll
        for (int c = 0; c < 8; ++c) {
            uint32_t bx = (c >> 2) & 1, by = (c >> 1) & 1, bz = c & 1;
            uint32_t h = (ix + bx)
                       ^ ((iy + by) * 2654435761u)
                       ^ ((iz + bz) * 805459861u);
            uint32_t idx = base + (h & 0x7FFFFu);
            float w = (bx ? wx : 1.f - wx) * (by ? wy : 1.f - wy) * (bz ? wz : 1.f - wz);
            float2 v = unpack_bf16x2(tab[idx]);
            sx = fmaf(w, v.x, sx);
            sy = fmaf(w, v.y, sy);
        }
        *(float2*)(out + (size_t)p * 32 + 2 * l) = make_float2(sx, sy);
    }
}

// ------------------------------------------------- fused fallback (tiny ws)
__global__ __launch_bounds__(256) void fused_fallback_kernel(
    const float* __restrict__ xyz, const int* __restrict__ rays,
    const float* __restrict__ expw,
    const float2* __restrict__ mean, const float2* __restrict__ emb,
    float* __restrict__ out)
{
    int p = blockIdx.x * 256 + threadIdx.x;
    if (p >= NPOINTS) return;
    float x = xyz[3 * p], y = xyz[3 * p + 1], z = xyz[3 * p + 2];
    int frame = (rays[p] >> 10) & 3;
    float e[8];
#pragma unroll
    for (int b = 0; b < 8; ++b) e[b] = expw[8 * frame + b];

    constexpr uint32_t OFFS[16] = OFFS_INIT;

    for (int l = 0; l < 16; ++l) {
        float scale = (float)((16 << l) - 1);
        float px = fmaf(x, scale, 0.5f);
        float py = fmaf(y, scale, 0.5f);
        float pz = fmaf(z, scale, 0.5f);
        float fx = floorf(px), fy = floorf(py), fz = floorf(pz);
        float wx = px - fx, wy = py - fy, wz = pz - fz;
        int ix = (int)fx, iy = (int)fy, iz = (int)fz;
        uint32_t base = OFFS[l];
        float sx = 0.f, sy = 0.f;
#pragma unroll
        for (int c = 0; c < 8; ++c) {
            int bx = (c >> 2) & 1, by = (c >> 1) & 1, bz = c & 1;
            uint32_t idx;
            if (l < 3) {
                uint32_t st = (l == 0) ? 17u : (l == 1) ? 33u : 65u;
                idx = (uint32_t)(ix + bx) + (uint32_t)(iy + by) * st
                    + (uint32_t)(iz + bz) * st * st;
            } else {
                idx = ((uint32_t)(ix + bx)
                     ^ ((uint32_t)(iy + by) * 2654435761u)
                     ^ ((uint32_t)(iz + bz) * 805459861u)) & 0x7FFFFu;
            }
            uint32_t g = base + idx;
            float2 m = mean[g];
            float vx = e[0] * m.x, vy = e[0] * m.y;
#pragma unroll
            for (int b = 0; b < 7; ++b) {
                float2 t = emb[(size_t)b * TOTAL_T + g];
                vx = fmaf(e[1 + b], t.x, vx);
                vy = fmaf(e[1 + b], t.y, vy);
            }
            float w = (bx ? wx : 1.f - wx) * (by ? wy : 1.f - wy) * (bz ? wz : 1.f - wz);
            sx = fmaf(w, vx, sx);
            sy = fmaf(w, vy, sy);
        }
        out[(size_t)p * 32 + 2 * l]     = sx;
        out[(size_t)p * 32 + 2 * l + 1] = sy;
    }
}

// ---------------------------------------------------------------- launch
extern "C" void kernel_launch(void* const* d_in, const int* in_sizes, int n_in,
                              void* d_out, int out_size, void* d_ws, size_t ws_size,
                              hipStream_t stream) {
    const float* inputs = (const float*)d_in[0];
    const float* expw   = (const float*)d_in[1];
    const float* mean   = (const float*)d_in[2];
    const float* emb    = (const float*)d_in[3];
    const int*   rays   = (const int*)d_in[4];
    float* out = (float*)d_out;

    char* wsb = (char*)d_ws;

    if (ws_size >= NEED_V4) {
        uint32_t* cur   = (uint32_t*)(wsb + OFF_CUR);
        float4*   sxyzf = (float4*)(wsb + OFF_SXYZF);
        uint32_t* sperm = (uint32_t*)(wsb + OFF_SPERM);
        uint32_t* ctrs  = (uint32_t*)(wsb + OFF_CTRS);
        float2*   ws2   = (float2*)(wsb + OFF_WS);

        blend_mlp_kernel<<<BLEND_BLOCKS, 256, 0, stream>>>(
            (const float2*)mean, (const float2*)emb, expw, cur);
        sort_init_kernel<<<1, 64, 0, stream>>>(ctrs);
        sort_count_kernel<<<NPOINTS / 256, 256, 0, stream>>>(rays, ctrs);
        sort_scatter_kernel<<<NPOINTS / 256, 256, 0, stream>>>(
            inputs, rays, ctrs, sperm, sxyzf);
        gather_lvl_kernel<<<14 * 2048, 256, 0, stream>>>(sxyzf, cur, ws2);
        merge_out_kernel<<<NPOINTS / 256, 256, 0, stream>>>(sperm, ws2, out);
    } else if (ws_size >= NEED_V3) {
        uint32_t* cur = (uint32_t*)d_ws;
        blend_mlp_kernel<<<BLEND_BLOCKS, 256, 0, stream>>>(
            (const float2*)mean, (const float2*)emb, expw, cur);
        gather_legacy_kernel<<<14 * 2048, 256, 0, stream>>>(
            inputs, rays, cur, out);
    } else {
        fused_fallback_kernel<<<NPOINTS / 256, 256, 0, stream>>>(
            inputs, rays, expw, (const float2*)mean, (const float2*)emb, out);
    }
}